// Round 11
// baseline (90.866 us; speedup 1.0000x reference)
//
#include <hip/hip_runtime.h>
#include <stdint.h>

// Keep float math un-fused so IoU bits match the numpy/JAX reference near the
// 0.6 / 0.3 mask thresholds.
#pragma clang fp contract(off)

#define BB 4
#define GG 64
#define AA 262144
#define TT 256
#define PP 128
#define APT 4                 // anchors per thread in k_scan (r5/r7-verified)
#define NEG_THRESH 0.99f      // stored negs ~2600/batch; top-256 boundary ~0.9988
#define NBINS 2048
#define CANDCAP 1024
#define NT_SEL 512
#define CB (NBINS / NT_SEL)   // bins per chunk = 4
#define SCAN_NT 256
#define BLK_ANCH (SCAN_NT * APT)   // 1024 anchors per block
#define GUNROLL 8             // gt count padded to a multiple of 8

// ---------------- Threefry-2x32 (matches jax._src.prng) ----------------
__host__ __device__ inline void tf2x32(uint32_t k0, uint32_t k1,
                                       uint32_t x0, uint32_t x1,
                                       uint32_t& o0, uint32_t& o1) {
  const uint32_t ks2 = k0 ^ k1 ^ 0x1BD11BDAu;
  x0 += k0; x1 += k1;
#define TF_R(r) { x0 += x1; x1 = (x1 << (r)) | (x1 >> (32 - (r))); x1 ^= x0; }
  TF_R(13) TF_R(15) TF_R(26) TF_R(6)
  x0 += k1;  x1 += ks2 + 1u;
  TF_R(17) TF_R(29) TF_R(16) TF_R(24)
  x0 += ks2; x1 += k0 + 2u;
  TF_R(13) TF_R(15) TF_R(26) TF_R(6)
  x0 += k0;  x1 += k1 + 3u;
  TF_R(17) TF_R(29) TF_R(16) TF_R(24)
  x0 += k1;  x1 += ks2 + 4u;
  TF_R(13) TF_R(15) TF_R(26) TF_R(6)
  x0 += ks2; x1 += k0 + 5u;
#undef TF_R
  o0 = x0; o1 = x1;
}

// jax.random.uniform, threefry_partitionable path: bits[i] = o0^o1 of
// block(key, (0, i)); value = bitcast((bits>>9)|0x3f800000) - 1.0
__device__ inline float tf_uniform(uint32_t k0, uint32_t k1, uint32_t idx) {
  uint32_t o0, o1;
  tf2x32(k0, k1, 0u, idx, o0, o1);
  uint32_t bits = o0 ^ o1;
  return __uint_as_float((bits >> 9) | 0x3f800000u) - 1.0f;
}

// key layout: [63:32] priority float bits, [23:6] ~a (18 bits), [5:0] gt idx.
// Desc sort == JAX top_k order (value desc, index asc); a unique -> g bits
// never decide order.
__device__ inline unsigned long long make_key(float pri, int a, int g) {
  const uint32_t inv = (uint32_t)a ^ 0x3FFFFu;
  return ((unsigned long long)__float_as_uint(pri) << 32) |
         ((unsigned long long)inv << 6) | (unsigned)g;
}

// Compile-time-trip scan body: identical math to r7's verified loop; the
// constant NG lets the compiler fully unroll and software-pipeline the LDS
// reads across the whole sequence (r7 showed 71% VALU busy this way).
template <int NG>
__device__ inline void scan_gts(const float4* __restrict__ s_gt,
                                const float* __restrict__ s_area,
                                const float4* an, const float* area_an,
                                float* best, int* bestg) {
#pragma unroll
  for (int g = 0; g < NG; ++g) {
    const float4 gb = s_gt[g];
    const float area_gt = s_area[g];
#pragma unroll
    for (int k = 0; k < APT; ++k) {
      float iw = fmaxf(0.f, fminf(gb.w, an[k].w) - fmaxf(gb.y, an[k].y));
      float ih = fmaxf(0.f, fminf(gb.z, an[k].z) - fmaxf(gb.x, an[k].x));
      float inter = iw * ih;
      float iou = inter / (area_gt + area_an[k] - inter);
      if (iou > best[k]) { best[k] = iou; bestg[k] = g; }
    }
  }
}

// ---------------- Kernel 1: IoU scan + block-aggregated candidate store ----
__global__ __launch_bounds__(SCAN_NT) void k_scan(
    const float* __restrict__ gt_boxes,   // (B, G, 5)
    const float* __restrict__ gt_cls,     // (B, G, 3)
    const float* __restrict__ anchors,    // (B, A, 4)
    int* __restrict__ counters,           // per batch: npos, nneg, spos, sneg
    unsigned long long* __restrict__ pos_key,
    unsigned long long* __restrict__ neg_key,
    int cap_pos, int cap_neg,
    uint32_t kp0, uint32_t kp1, uint32_t kn0, uint32_t kn1) {
  __shared__ float4 s_gt[GG + GUNROLL];   // COMPACTED valid gts + zero pads
  __shared__ float s_area[GG + GUNROLL];
  __shared__ int s_gidx[GG];        // compacted slot -> original g
  __shared__ int s_ng;              // number of valid gts
  __shared__ unsigned long long l_buf[BLK_ANCH];  // pos from 0^, neg from top v
  __shared__ int l_cnt[4];     // pos stored, neg stored, npos, nneg
  __shared__ int l_base[2];

  const int BPB = AA / BLK_ANCH;                     // blocks per batch = 256
  const int b = blockIdx.x / BPB;
  const int base = (blockIdx.x % BPB) * BLK_ANCH;
  const int tid = threadIdx.x;
  const int lane = tid & 63;
  const unsigned long long below = (lane == 0) ? 0ull : (~0ull >> (64 - lane));

  // Valid-GT compaction (wave 0 only; GG == 64 == one wave).
  // Invalid gts give IoU == +0.0 (zero box) in the reference path -> can't
  // flip pos/neg or win argmax (strict >, iou >= 0) -> skipping is exact.
  // Pads (zero boxes after the compacted list, count padded to a multiple
  // of 8) are inert the same way; an all-pad row (ng==0) classifies as neg
  // exactly like the masked reference (iou_max == -1 there, 0 here; both
  // < 0.3 and not > 0.6).
  if (tid < GG) {
    bool v = gt_cls[(size_t)(b * GG + tid) * 3 + 2] != -1.0f;
    unsigned long long mv = __ballot(v);
    int cnt = __popcll(mv);
    if (v) {
      const float* gb = gt_boxes + (size_t)(b * GG + tid) * 5;
      int pos = __popcll(mv & below);
      s_gt[pos] = make_float4(gb[0], gb[1], gb[2], gb[3]);
      s_area[pos] = (gb[3] - gb[1]) * (gb[2] - gb[0]);
      s_gidx[pos] = tid;
    }
    if (tid < GUNROLL) {
      s_gt[cnt + tid] = make_float4(0.f, 0.f, 0.f, 0.f);
      s_area[cnt + tid] = 0.f;
    }
    if (tid == 0) s_ng = cnt;
  }
  if (tid < 4) l_cnt[tid] = 0;
  __syncthreads();
  const int ng = s_ng;
  const int ng8 = (ng + GUNROLL - 1) & ~(GUNROLL - 1);

  float4 an[APT];
  float area_an[APT], best[APT];
  int bestg[APT];
  const float4* ap = (const float4*)anchors + (size_t)b * AA + base + tid;
#pragma unroll
  for (int k = 0; k < APT; ++k) {
    an[k] = ap[k * SCAN_NT];
    area_an[k] = (an[k].w - an[k].y) * (an[k].z - an[k].x);
    best[k] = -1.0f;
    bestg[k] = 0;
  }

  // Dispatch to a compile-time trip count (ng8 is always a multiple of 8,
  // batch-uniform -> no divergence). Each case is a fully-unrolled
  // straight-line body the scheduler can pipeline like r7's fixed loop.
  switch (ng8) {
    case 0: break;
    case 8:  scan_gts<8>(s_gt, s_area, an, area_an, best, bestg); break;
    case 16: scan_gts<16>(s_gt, s_area, an, area_an, best, bestg); break;
    case 24: scan_gts<24>(s_gt, s_area, an, area_an, best, bestg); break;
    case 32: scan_gts<32>(s_gt, s_area, an, area_an, best, bestg); break;
    case 40: scan_gts<40>(s_gt, s_area, an, area_an, best, bestg); break;
    case 48: scan_gts<48>(s_gt, s_area, an, area_an, best, bestg); break;
    case 56: scan_gts<56>(s_gt, s_area, an, area_an, best, bestg); break;
    default: scan_gts<64>(s_gt, s_area, an, area_an, best, bestg); break;
  }

  // classify + stage candidates in LDS.
  // ALL ballots/shfls/leader-atomics execute at full-wave convergence;
  // only the LDS store itself is predicated.
#pragma unroll
  for (int k = 0; k < APT; ++k) {
    const int a = base + k * SCAN_NT + tid;
    const uint32_t flat = (uint32_t)(b * AA + a);
    const bool isp = best[k] > 0.6f;
    const bool isn = best[k] < 0.3f;

    float prin = 0.f;
    bool store_n = false;
    if (isn) {
      prin = tf_uniform(kn0, kn1, flat);
      store_n = prin > NEG_THRESH;
    }

    const unsigned long long mp = __ballot(isp);
    const unsigned long long mnAll = __ballot(isn);
    const unsigned long long mn = __ballot(store_n);

    int wbase_p = 0, wbase_n = 0;
    if (lane == 0) {
      const int cp = __popcll(mp);
      const int cs = __popcll(mn);
      const int cnAll = __popcll(mnAll);
      if (cp) { wbase_p = atomicAdd(&l_cnt[0], cp); atomicAdd(&l_cnt[2], cp); }
      if (cs) wbase_n = atomicAdd(&l_cnt[1], cs);
      if (cnAll) atomicAdd(&l_cnt[3], cnAll);
    }
    wbase_p = __shfl(wbase_p, 0);
    wbase_n = __shfl(wbase_n, 0);

    // pos + stored-neg are mutually exclusive per anchor, so the two ends
    // of l_buf can never collide (total <= BLK_ANCH by construction).
    if (isp) {
      float pri = tf_uniform(kp0, kp1, flat);
      l_buf[wbase_p + __popcll(mp & below)] =
          make_key(pri, a, s_gidx[bestg[k]]);
    }
    if (store_n) {
      l_buf[BLK_ANCH - 1 - (wbase_n + __popcll(mn & below))] =
          make_key(prin, a, 0);
    }
  }
  __syncthreads();

  // one returning device atomic per non-empty list per block
  if (tid == 0) {
    l_base[0] = l_cnt[0] ? atomicAdd(&counters[b * 4 + 2], l_cnt[0]) : 0;
    if (l_cnt[2]) atomicAdd(&counters[b * 4 + 0], l_cnt[2]);
  } else if (tid == 64) {
    l_base[1] = l_cnt[1] ? atomicAdd(&counters[b * 4 + 3], l_cnt[1]) : 0;
    if (l_cnt[3]) atomicAdd(&counters[b * 4 + 1], l_cnt[3]);
  }
  __syncthreads();

  // coalesced copy-out (prefix [0,cap) stays fully populated: a straddling
  // block writes only its in-range part; selection is order-independent)
  for (int i = tid; i < l_cnt[0]; i += SCAN_NT) {
    int dst = l_base[0] + i;
    if (dst < cap_pos) pos_key[(size_t)b * cap_pos + dst] = l_buf[i];
  }
  for (int i = tid; i < l_cnt[1]; i += SCAN_NT) {
    int dst = l_base[1] + i;
    if (dst < cap_neg)
      neg_key[(size_t)b * cap_neg + dst] = l_buf[BLK_ANCH - 1 - i];
  }
}

// ---------------- Kernel 2: exact histogram top-k + fused outputs ----------
// One block per (batch, phase). Phase 0 (pos) writes slots [0,pos_count) and
// the tail [pos_count+neg_count, 256) plus scalars/hits; phase 1 (neg)
// writes slots [pos_count, pos_count+neg_count). Disjoint, complete cover.
// out layout (flat float32):
//   class_ids [0, 2048), deltas [2048, 6144), indices [6144, 8192),
//   gt_num [8192, 8196), pos_count [8196, 8200), miss [8200, 8204)
__global__ __launch_bounds__(NT_SEL) void k_sel(
    const float* __restrict__ gt_boxes,
    const float* __restrict__ gt_cls,
    const float* __restrict__ anchors,
    const int* __restrict__ counters,
    const unsigned long long* __restrict__ pos_key,
    const unsigned long long* __restrict__ neg_key,
    int cap_pos, int cap_neg,
    float* __restrict__ out) {
  const int b = blockIdx.x >> 1;
  const int phase = blockIdx.x & 1;
  const int tid = threadIdx.x;

  __shared__ int hist[NBINS];
  __shared__ int chunk[NT_SEL];
  __shared__ unsigned long long cand[CANDCAP];
  __shared__ float4 s_gt[GG];
  __shared__ float s_cls0[GG], s_cls1[GG];
  __shared__ int s_valid[GG];
  __shared__ unsigned int hit_lo, hit_hi;
  __shared__ int s_t, s_cnt;

  if (tid < GG) {
    const float* gb = gt_boxes + (size_t)(b * GG + tid) * 5;
    s_gt[tid] = make_float4(gb[0], gb[1], gb[2], gb[3]);
    s_cls0[tid] = gt_cls[(size_t)(b * GG + tid) * 3 + 0];
    s_cls1[tid] = gt_cls[(size_t)(b * GG + tid) * 3 + 1];
    s_valid[tid] = (gt_cls[(size_t)(b * GG + tid) * 3 + 2] != -1.0f) ? 1 : 0;
  }
  if (tid == 0) { hit_lo = 0u; hit_hi = 0u; }

  const int npos = counters[b * 4 + 0];
  const int nneg = counters[b * 4 + 1];
  const int sp = min(counters[b * 4 + 2], cap_pos);
  const int sn = min(counters[b * 4 + 3], cap_neg);
  const int pos_count = min(min(PP, npos), sp);
  const int neg_count = min(min(TT - pos_count, nneg), sn);

  const unsigned long long* keys =
      phase ? neg_key + (size_t)b * cap_neg : pos_key + (size_t)b * cap_pos;
  const int n = phase ? sn : sp;
  const int kk = phase ? neg_count : pos_count;

  for (int i = tid; i < NBINS; i += NT_SEL) hist[i] = 0;
  if (tid == 0) { s_cnt = 0; s_t = (kk == 0) ? NBINS : 0; }
  __syncthreads();

  for (int i = tid; i < n; i += NT_SEL) {
    float pri = __uint_as_float((uint32_t)(keys[i] >> 32));
    int bin = min(NBINS - 1, (int)(pri * (float)NBINS));
    atomicAdd(&hist[bin], 1);
  }
  __syncthreads();

  // parallel suffix scan over 512 chunk sums (4 bins/chunk)
  {
    int c = 0;
#pragma unroll
    for (int u = 0; u < CB; ++u) c += hist[tid * CB + u];
    chunk[tid] = c;
    __syncthreads();
    for (int s = 1; s < NT_SEL; s <<= 1) {
      int v = chunk[tid];
      int add = (tid + s < NT_SEL) ? chunk[tid + s] : 0;
      __syncthreads();
      chunk[tid] = v + add;
      __syncthreads();
    }
    // t = max{bin : suffix(bin) >= kk}; crossing chunk unique (monotone).
    if (kk > 0) {
      int Scur = chunk[tid];
      int Snext = (tid + 1 < NT_SEL) ? chunk[tid + 1] : 0;
      if (Scur >= kk && Snext < kk) {
        int acc = Snext;
        for (int u = CB - 1; u >= 0; --u) {
          acc += hist[tid * CB + u];
          if (acc >= kk) { s_t = tid * CB + u; break; }
        }
      }
      // if chunk[0] < kk (n < kk): no chunk qualifies, s_t stays 0 -> all n
    }
  }
  __syncthreads();
  const int t = s_t;

  for (int i = tid; i < n; i += NT_SEL) {
    unsigned long long key = keys[i];
    float pri = __uint_as_float((uint32_t)(key >> 32));
    int bin = min(NBINS - 1, (int)(pri * (float)NBINS));
    if (bin >= t) {
      int slot = atomicAdd(&s_cnt, 1);
      if (slot < CANDCAP) cand[slot] = key;
    }
  }
  __syncthreads();
  const int cnt = min(s_cnt, CANDCAP);  // cnt >= kk by suffix construction

  unsigned m = 1;
  while (m < (unsigned)cnt) m <<= 1;   // sort size: next pow2 of cnt
  for (int i = tid; i < (int)m; i += NT_SEL)
    if (i >= cnt) cand[i] = 0ull;
  __syncthreads();

  for (unsigned kq = 2; kq <= m; kq <<= 1) {
    for (unsigned s = kq >> 1; s > 0; s >>= 1) {
      for (unsigned i = tid; i < m; i += NT_SEL) {
        unsigned p = i ^ s;
        if (p > i) {
          unsigned long long x = cand[i], y = cand[p];
          if (((i & kq) == 0) ? (x < y) : (x > y)) { cand[i] = y; cand[p] = x; }
        }
      }
      __syncthreads();
    }
  }
  // cand[0..kk) now holds this phase's selected keys in JAX top_k order.

  // ---- fused output writing ----
  if (tid < TT) {
    const int j = tid;
    if (phase == 0) {
      const bool isp = j < pos_count;
      const bool tail = j >= pos_count + neg_count;   // tag -1 region
      if (isp || tail) {
        float c0 = 0.f, c1 = 0.f, d0 = 0.f, d1 = 0.f, d2 = 0.f, d3 = 0.f;
        int out_idx = -1, tag = -1;
        if (isp) {
          const unsigned long long key = cand[j];
          const int a = (int)((((unsigned)(key >> 6)) & 0x3FFFFu) ^ 0x3FFFFu);
          const int g = (int)(key & 63ull);
          out_idx = a; tag = 1;
          c0 = s_cls0[g]; c1 = s_cls1[g];
          float4 an = ((const float4*)anchors)[(size_t)b * AA + a];
          float4 gb = s_gt[g];
          float h = an.z - an.x, w = an.w - an.y;
          float gh = gb.z - gb.x, gw = gb.w - gb.y;
          float cy = (an.z + an.x) * 0.5f, cx = (an.w + an.y) * 0.5f;
          float gcy = (gb.z + gb.x) * 0.5f, gcx = (gb.w + gb.y) * 0.5f;
          d0 = ((gcy - cy) / h) / 0.1f;
          d1 = ((gcx - cx) / w) / 0.1f;
          d2 = logf(gh / h) / 0.2f;
          d3 = logf(gw / w) / 0.2f;
          if (g < 32) atomicOr(&hit_lo, 1u << g);
          else        atomicOr(&hit_hi, 1u << (g - 32));
        }
        float* cls_out = out + ((size_t)b * TT + j) * 2;
        cls_out[0] = c0; cls_out[1] = c1;
        float* del_out = out + 2048 + ((size_t)b * TT + j) * 4;
        del_out[0] = d0; del_out[1] = d1; del_out[2] = d2; del_out[3] = d3;
        float* idx_out = out + 6144 + ((size_t)b * TT + j) * 2;
        idx_out[0] = (float)out_idx; idx_out[1] = (float)tag;
      }
    } else {
      const bool isn = (j >= pos_count) && (j < pos_count + neg_count);
      if (isn) {
        const unsigned long long key = cand[j - pos_count];
        const int a = (int)((((unsigned)(key >> 6)) & 0x3FFFFu) ^ 0x3FFFFu);
        float* cls_out = out + ((size_t)b * TT + j) * 2;
        cls_out[0] = 1.f; cls_out[1] = 0.f;
        float* del_out = out + 2048 + ((size_t)b * TT + j) * 4;
        del_out[0] = 0.f; del_out[1] = 0.f; del_out[2] = 0.f; del_out[3] = 0.f;
        float* idx_out = out + 6144 + ((size_t)b * TT + j) * 2;
        idx_out[0] = (float)a; idx_out[1] = 0.f;
      }
    }
  }

  __syncthreads();
  if (phase == 0 && tid == 0) {
    int gn = 0;
    for (int g = 0; g < GG; ++g) gn += s_valid[g];
    float hits = (float)(__popc(hit_lo) + __popc(hit_hi));
    out[8192 + b] = (float)gn;
    out[8196 + b] = (float)pos_count;
    out[8200 + b] = (float)gn - hits;
  }
}

// ---------------- host ----------------
extern "C" void kernel_launch(void* const* d_in, const int* in_sizes, int n_in,
                              void* d_out, int out_size, void* d_ws, size_t ws_size,
                              hipStream_t stream) {
  const float* gt_boxes = (const float*)d_in[0];
  const float* gt_cls   = (const float*)d_in[1];
  const float* anchors  = (const float*)d_in[2];
  float* out = (float*)d_out;

  // folded keys: key(42) = (0,42); fold_in(k, d) = threefry block on (0, d)
  uint32_t kp0, kp1, kn0, kn1;
  tf2x32(0u, 42u, 0u, 0u, kp0, kp1);   // pri_pos key
  tf2x32(0u, 42u, 0u, 1u, kn0, kn1);   // pri_neg key

  // ws layout: [256B counters][pos_key B*cap_pos*8][neg_key B*cap_neg*8]
  long cap_pos = 32768, cap_neg = 8192;
  while (cap_pos > 2048 &&
         256 + (size_t)BB * 8 * (size_t)(cap_pos + cap_neg) > ws_size) {
    cap_pos >>= 1; cap_neg >>= 1;
  }
  char* base = (char*)d_ws;
  int* counters = (int*)base;
  unsigned long long* pos_key = (unsigned long long*)(base + 256);
  unsigned long long* neg_key = pos_key + (size_t)BB * cap_pos;

  hipMemsetAsync(d_ws, 0, 256, stream);
  k_scan<<<BB * (AA / BLK_ANCH), SCAN_NT, 0, stream>>>(
      gt_boxes, gt_cls, anchors, counters, pos_key, neg_key,
      (int)cap_pos, (int)cap_neg, kp0, kp1, kn0, kn1);
  k_sel<<<BB * 2, NT_SEL, 0, stream>>>(
      gt_boxes, gt_cls, anchors, counters, pos_key, neg_key,
      (int)cap_pos, (int)cap_neg, out);
}

// Round 12
// 87.689 us; speedup vs baseline: 1.0362x; 1.0362x over previous
//
#include <hip/hip_runtime.h>
#include <stdint.h>

// Keep float math un-fused so IoU bits match the numpy/JAX reference near the
// 0.6 / 0.3 mask thresholds.
#pragma clang fp contract(off)

#define BB 4
#define GG 64
#define AA 262144
#define TT 256
#define PP 128
#define APT 2                 // anchors per thread (TLP: 32 waves/CU)
#define NEG_THRESH 0.99f      // stored negs ~2600/batch; top-256 boundary ~0.9988
#define NBINS 2048
#define CANDCAP 1024
#define NT_SEL 512
#define CB (NBINS / NT_SEL)   // bins per chunk = 4
#define SCAN_NT 512           // 8 waves/block; block count unchanged vs r10
#define BLK_ANCH (SCAN_NT * APT)   // 1024 anchors per block
#define GUNROLL 8             // gt count padded to a multiple of 8

// ---------------- Threefry-2x32 (matches jax._src.prng) ----------------
__host__ __device__ inline void tf2x32(uint32_t k0, uint32_t k1,
                                       uint32_t x0, uint32_t x1,
                                       uint32_t& o0, uint32_t& o1) {
  const uint32_t ks2 = k0 ^ k1 ^ 0x1BD11BDAu;
  x0 += k0; x1 += k1;
#define TF_R(r) { x0 += x1; x1 = (x1 << (r)) | (x1 >> (32 - (r))); x1 ^= x0; }
  TF_R(13) TF_R(15) TF_R(26) TF_R(6)
  x0 += k1;  x1 += ks2 + 1u;
  TF_R(17) TF_R(29) TF_R(16) TF_R(24)
  x0 += ks2; x1 += k0 + 2u;
  TF_R(13) TF_R(15) TF_R(26) TF_R(6)
  x0 += k0;  x1 += k1 + 3u;
  TF_R(17) TF_R(29) TF_R(16) TF_R(24)
  x0 += k1;  x1 += ks2 + 4u;
  TF_R(13) TF_R(15) TF_R(26) TF_R(6)
  x0 += ks2; x1 += k0 + 5u;
#undef TF_R
  o0 = x0; o1 = x1;
}

// jax.random.uniform, threefry_partitionable path: bits[i] = o0^o1 of
// block(key, (0, i)); value = bitcast((bits>>9)|0x3f800000) - 1.0
__device__ inline float tf_uniform(uint32_t k0, uint32_t k1, uint32_t idx) {
  uint32_t o0, o1;
  tf2x32(k0, k1, 0u, idx, o0, o1);
  uint32_t bits = o0 ^ o1;
  return __uint_as_float((bits >> 9) | 0x3f800000u) - 1.0f;
}

// key layout: [63:32] priority float bits, [23:6] ~a (18 bits), [5:0] gt idx.
// Desc sort == JAX top_k order (value desc, index asc); a unique -> g bits
// never decide order.
__device__ inline unsigned long long make_key(float pri, int a, int g) {
  const uint32_t inv = (uint32_t)a ^ 0x3FFFFu;
  return ((unsigned long long)__float_as_uint(pri) << 32) |
         ((unsigned long long)inv << 6) | (unsigned)g;
}

// ---------------- Kernel 1: IoU scan + block-aggregated candidate store ----
__global__ __launch_bounds__(SCAN_NT) void k_scan(
    const float* __restrict__ gt_boxes,   // (B, G, 5)
    const float* __restrict__ gt_cls,     // (B, G, 3)
    const float* __restrict__ anchors,    // (B, A, 4)
    int* __restrict__ counters,           // per batch: npos, nneg, spos, sneg
    unsigned long long* __restrict__ pos_key,
    unsigned long long* __restrict__ neg_key,
    int cap_pos, int cap_neg,
    uint32_t kp0, uint32_t kp1, uint32_t kn0, uint32_t kn1) {
  __shared__ float4 s_gt[GG + GUNROLL];   // COMPACTED valid gts + zero pads
  __shared__ float s_area[GG + GUNROLL];
  __shared__ int s_gidx[GG];        // compacted slot -> original g
  __shared__ int s_ng;              // number of valid gts
  __shared__ unsigned long long l_buf[BLK_ANCH];  // pos from 0^, neg from top v
  __shared__ int l_cnt[4];     // pos stored, neg stored, npos, nneg
  __shared__ int l_base[2];

  const int BPB = AA / BLK_ANCH;                     // blocks per batch = 256
  const int b = blockIdx.x / BPB;
  const int base = (blockIdx.x % BPB) * BLK_ANCH;
  const int tid = threadIdx.x;
  const int lane = tid & 63;
  const unsigned long long below = (lane == 0) ? 0ull : (~0ull >> (64 - lane));

  // Valid-GT compaction (wave 0 only; GG == 64 == one wave).
  // Invalid gts give IoU == +0.0 (zero box) in the reference path -> can't
  // flip pos/neg or win argmax (strict >, iou >= 0) -> skipping is exact.
  // Pads (zero boxes after the compacted list, count padded to a multiple
  // of 8) are inert the same way; an all-pad row (ng==0) classifies as neg
  // exactly like the masked reference.
  if (tid < GG) {
    bool v = gt_cls[(size_t)(b * GG + tid) * 3 + 2] != -1.0f;
    unsigned long long mv = __ballot(v);
    int cnt = __popcll(mv);
    if (v) {
      const float* gb = gt_boxes + (size_t)(b * GG + tid) * 5;
      int pos = __popcll(mv & below);
      s_gt[pos] = make_float4(gb[0], gb[1], gb[2], gb[3]);
      s_area[pos] = (gb[3] - gb[1]) * (gb[2] - gb[0]);
      s_gidx[pos] = tid;
    }
    if (tid < GUNROLL) {
      s_gt[cnt + tid] = make_float4(0.f, 0.f, 0.f, 0.f);
      s_area[cnt + tid] = 0.f;
    }
    if (tid == 0) s_ng = cnt;
  }
  if (tid < 4) l_cnt[tid] = 0;
  __syncthreads();
  const int ng = s_ng;
  const int ng8 = (ng + GUNROLL - 1) & ~(GUNROLL - 1);

  float4 an[APT];
  float area_an[APT], best[APT];
  int bestg[APT];
  const float4* ap = (const float4*)anchors + (size_t)b * AA + base + tid;
#pragma unroll
  for (int k = 0; k < APT; ++k) {
    an[k] = ap[k * SCAN_NT];
    area_an[k] = (an[k].w - an[k].y) * (an[k].z - an[k].x);
    best[k] = -1.0f;
    bestg[k] = 0;
  }

  // Runtime loop stepping by GUNROLL with a compile-time-unrolled body
  // (r10-verified codegen); latency now hidden by 2x wave count (TLP).
  for (int gi = 0; gi < ng8; gi += GUNROLL) {
#pragma unroll
    for (int u = 0; u < GUNROLL; ++u) {
      const float4 gb = s_gt[gi + u];
      const float area_gt = s_area[gi + u];
#pragma unroll
      for (int k = 0; k < APT; ++k) {
        float iw = fmaxf(0.f, fminf(gb.w, an[k].w) - fmaxf(gb.y, an[k].y));
        float ih = fmaxf(0.f, fminf(gb.z, an[k].z) - fmaxf(gb.x, an[k].x));
        float inter = iw * ih;
        float iou = inter / (area_gt + area_an[k] - inter);
        if (iou > best[k]) { best[k] = iou; bestg[k] = gi + u; }
      }
    }
  }

  // classify + stage candidates in LDS.
  // ALL ballots/shfls/leader-atomics execute at full-wave convergence;
  // only the LDS store itself is predicated.
#pragma unroll
  for (int k = 0; k < APT; ++k) {
    const int a = base + k * SCAN_NT + tid;
    const uint32_t flat = (uint32_t)(b * AA + a);
    const bool isp = best[k] > 0.6f;
    const bool isn = best[k] < 0.3f;

    float prin = 0.f;
    bool store_n = false;
    if (isn) {
      prin = tf_uniform(kn0, kn1, flat);
      store_n = prin > NEG_THRESH;
    }

    const unsigned long long mp = __ballot(isp);
    const unsigned long long mnAll = __ballot(isn);
    const unsigned long long mn = __ballot(store_n);

    int wbase_p = 0, wbase_n = 0;
    if (lane == 0) {
      const int cp = __popcll(mp);
      const int cs = __popcll(mn);
      const int cnAll = __popcll(mnAll);
      if (cp) { wbase_p = atomicAdd(&l_cnt[0], cp); atomicAdd(&l_cnt[2], cp); }
      if (cs) wbase_n = atomicAdd(&l_cnt[1], cs);
      if (cnAll) atomicAdd(&l_cnt[3], cnAll);
    }
    wbase_p = __shfl(wbase_p, 0);
    wbase_n = __shfl(wbase_n, 0);

    // pos + stored-neg are mutually exclusive per anchor, so the two ends
    // of l_buf can never collide (total <= BLK_ANCH by construction).
    if (isp) {
      float pri = tf_uniform(kp0, kp1, flat);
      l_buf[wbase_p + __popcll(mp & below)] =
          make_key(pri, a, s_gidx[bestg[k]]);
    }
    if (store_n) {
      l_buf[BLK_ANCH - 1 - (wbase_n + __popcll(mn & below))] =
          make_key(prin, a, 0);
    }
  }
  __syncthreads();

  // one returning device atomic per non-empty list per block
  if (tid == 0) {
    l_base[0] = l_cnt[0] ? atomicAdd(&counters[b * 4 + 2], l_cnt[0]) : 0;
    if (l_cnt[2]) atomicAdd(&counters[b * 4 + 0], l_cnt[2]);
  } else if (tid == 64) {
    l_base[1] = l_cnt[1] ? atomicAdd(&counters[b * 4 + 3], l_cnt[1]) : 0;
    if (l_cnt[3]) atomicAdd(&counters[b * 4 + 1], l_cnt[3]);
  }
  __syncthreads();

  // coalesced copy-out (prefix [0,cap) stays fully populated: a straddling
  // block writes only its in-range part; selection is order-independent)
  for (int i = tid; i < l_cnt[0]; i += SCAN_NT) {
    int dst = l_base[0] + i;
    if (dst < cap_pos) pos_key[(size_t)b * cap_pos + dst] = l_buf[i];
  }
  for (int i = tid; i < l_cnt[1]; i += SCAN_NT) {
    int dst = l_base[1] + i;
    if (dst < cap_neg)
      neg_key[(size_t)b * cap_neg + dst] = l_buf[BLK_ANCH - 1 - i];
  }
}

// ---------------- Kernel 2: exact histogram top-k + fused outputs ----------
// One block per (batch, phase). Phase 0 (pos) writes slots [0,pos_count) and
// the tail [pos_count+neg_count, 256) plus scalars/hits; phase 1 (neg)
// writes slots [pos_count, pos_count+neg_count). Disjoint, complete cover.
// out layout (flat float32):
//   class_ids [0, 2048), deltas [2048, 6144), indices [6144, 8192),
//   gt_num [8192, 8196), pos_count [8196, 8200), miss [8200, 8204)
__global__ __launch_bounds__(NT_SEL) void k_sel(
    const float* __restrict__ gt_boxes,
    const float* __restrict__ gt_cls,
    const float* __restrict__ anchors,
    const int* __restrict__ counters,
    const unsigned long long* __restrict__ pos_key,
    const unsigned long long* __restrict__ neg_key,
    int cap_pos, int cap_neg,
    float* __restrict__ out) {
  const int b = blockIdx.x >> 1;
  const int phase = blockIdx.x & 1;
  const int tid = threadIdx.x;

  __shared__ int hist[NBINS];
  __shared__ int chunk[NT_SEL];
  __shared__ unsigned long long cand[CANDCAP];
  __shared__ float4 s_gt[GG];
  __shared__ float s_cls0[GG], s_cls1[GG];
  __shared__ int s_valid[GG];
  __shared__ unsigned int hit_lo, hit_hi;
  __shared__ int s_t, s_cnt;

  if (tid < GG) {
    const float* gb = gt_boxes + (size_t)(b * GG + tid) * 5;
    s_gt[tid] = make_float4(gb[0], gb[1], gb[2], gb[3]);
    s_cls0[tid] = gt_cls[(size_t)(b * GG + tid) * 3 + 0];
    s_cls1[tid] = gt_cls[(size_t)(b * GG + tid) * 3 + 1];
    s_valid[tid] = (gt_cls[(size_t)(b * GG + tid) * 3 + 2] != -1.0f) ? 1 : 0;
  }
  if (tid == 0) { hit_lo = 0u; hit_hi = 0u; }

  const int npos = counters[b * 4 + 0];
  const int nneg = counters[b * 4 + 1];
  const int sp = min(counters[b * 4 + 2], cap_pos);
  const int sn = min(counters[b * 4 + 3], cap_neg);
  const int pos_count = min(min(PP, npos), sp);
  const int neg_count = min(min(TT - pos_count, nneg), sn);

  const unsigned long long* keys =
      phase ? neg_key + (size_t)b * cap_neg : pos_key + (size_t)b * cap_pos;
  const int n = phase ? sn : sp;
  const int kk = phase ? neg_count : pos_count;

  for (int i = tid; i < NBINS; i += NT_SEL) hist[i] = 0;
  if (tid == 0) { s_cnt = 0; s_t = (kk == 0) ? NBINS : 0; }
  __syncthreads();

  for (int i = tid; i < n; i += NT_SEL) {
    float pri = __uint_as_float((uint32_t)(keys[i] >> 32));
    int bin = min(NBINS - 1, (int)(pri * (float)NBINS));
    atomicAdd(&hist[bin], 1);
  }
  __syncthreads();

  // parallel suffix scan over 512 chunk sums (4 bins/chunk)
  {
    int c = 0;
#pragma unroll
    for (int u = 0; u < CB; ++u) c += hist[tid * CB + u];
    chunk[tid] = c;
    __syncthreads();
    for (int s = 1; s < NT_SEL; s <<= 1) {
      int v = chunk[tid];
      int add = (tid + s < NT_SEL) ? chunk[tid + s] : 0;
      __syncthreads();
      chunk[tid] = v + add;
      __syncthreads();
    }
    // t = max{bin : suffix(bin) >= kk}; crossing chunk unique (monotone).
    if (kk > 0) {
      int Scur = chunk[tid];
      int Snext = (tid + 1 < NT_SEL) ? chunk[tid + 1] : 0;
      if (Scur >= kk && Snext < kk) {
        int acc = Snext;
        for (int u = CB - 1; u >= 0; --u) {
          acc += hist[tid * CB + u];
          if (acc >= kk) { s_t = tid * CB + u; break; }
        }
      }
      // if chunk[0] < kk (n < kk): no chunk qualifies, s_t stays 0 -> all n
    }
  }
  __syncthreads();
  const int t = s_t;

  for (int i = tid; i < n; i += NT_SEL) {
    unsigned long long key = keys[i];
    float pri = __uint_as_float((uint32_t)(key >> 32));
    int bin = min(NBINS - 1, (int)(pri * (float)NBINS));
    if (bin >= t) {
      int slot = atomicAdd(&s_cnt, 1);
      if (slot < CANDCAP) cand[slot] = key;
    }
  }
  __syncthreads();
  const int cnt = min(s_cnt, CANDCAP);  // cnt >= kk by suffix construction

  unsigned m = 1;
  while (m < (unsigned)cnt) m <<= 1;   // sort size: next pow2 of cnt
  for (int i = tid; i < (int)m; i += NT_SEL)
    if (i >= cnt) cand[i] = 0ull;
  __syncthreads();

  for (unsigned kq = 2; kq <= m; kq <<= 1) {
    for (unsigned s = kq >> 1; s > 0; s >>= 1) {
      for (unsigned i = tid; i < m; i += NT_SEL) {
        unsigned p = i ^ s;
        if (p > i) {
          unsigned long long x = cand[i], y = cand[p];
          if (((i & kq) == 0) ? (x < y) : (x > y)) { cand[i] = y; cand[p] = x; }
        }
      }
      __syncthreads();
    }
  }
  // cand[0..kk) now holds this phase's selected keys in JAX top_k order.

  // ---- fused output writing ----
  if (tid < TT) {
    const int j = tid;
    if (phase == 0) {
      const bool isp = j < pos_count;
      const bool tail = j >= pos_count + neg_count;   // tag -1 region
      if (isp || tail) {
        float c0 = 0.f, c1 = 0.f, d0 = 0.f, d1 = 0.f, d2 = 0.f, d3 = 0.f;
        int out_idx = -1, tag = -1;
        if (isp) {
          const unsigned long long key = cand[j];
          const int a = (int)((((unsigned)(key >> 6)) & 0x3FFFFu) ^ 0x3FFFFu);
          const int g = (int)(key & 63ull);
          out_idx = a; tag = 1;
          c0 = s_cls0[g]; c1 = s_cls1[g];
          float4 an = ((const float4*)anchors)[(size_t)b * AA + a];
          float4 gb = s_gt[g];
          float h = an.z - an.x, w = an.w - an.y;
          float gh = gb.z - gb.x, gw = gb.w - gb.y;
          float cy = (an.z + an.x) * 0.5f, cx = (an.w + an.y) * 0.5f;
          float gcy = (gb.z + gb.x) * 0.5f, gcx = (gb.w + gb.y) * 0.5f;
          d0 = ((gcy - cy) / h) / 0.1f;
          d1 = ((gcx - cx) / w) / 0.1f;
          d2 = logf(gh / h) / 0.2f;
          d3 = logf(gw / w) / 0.2f;
          if (g < 32) atomicOr(&hit_lo, 1u << g);
          else        atomicOr(&hit_hi, 1u << (g - 32));
        }
        float* cls_out = out + ((size_t)b * TT + j) * 2;
        cls_out[0] = c0; cls_out[1] = c1;
        float* del_out = out + 2048 + ((size_t)b * TT + j) * 4;
        del_out[0] = d0; del_out[1] = d1; del_out[2] = d2; del_out[3] = d3;
        float* idx_out = out + 6144 + ((size_t)b * TT + j) * 2;
        idx_out[0] = (float)out_idx; idx_out[1] = (float)tag;
      }
    } else {
      const bool isn = (j >= pos_count) && (j < pos_count + neg_count);
      if (isn) {
        const unsigned long long key = cand[j - pos_count];
        const int a = (int)((((unsigned)(key >> 6)) & 0x3FFFFu) ^ 0x3FFFFu);
        float* cls_out = out + ((size_t)b * TT + j) * 2;
        cls_out[0] = 1.f; cls_out[1] = 0.f;
        float* del_out = out + 2048 + ((size_t)b * TT + j) * 4;
        del_out[0] = 0.f; del_out[1] = 0.f; del_out[2] = 0.f; del_out[3] = 0.f;
        float* idx_out = out + 6144 + ((size_t)b * TT + j) * 2;
        idx_out[0] = (float)a; idx_out[1] = 0.f;
      }
    }
  }

  __syncthreads();
  if (phase == 0 && tid == 0) {
    int gn = 0;
    for (int g = 0; g < GG; ++g) gn += s_valid[g];
    float hits = (float)(__popc(hit_lo) + __popc(hit_hi));
    out[8192 + b] = (float)gn;
    out[8196 + b] = (float)pos_count;
    out[8200 + b] = (float)gn - hits;
  }
}

// ---------------- host ----------------
extern "C" void kernel_launch(void* const* d_in, const int* in_sizes, int n_in,
                              void* d_out, int out_size, void* d_ws, size_t ws_size,
                              hipStream_t stream) {
  const float* gt_boxes = (const float*)d_in[0];
  const float* gt_cls   = (const float*)d_in[1];
  const float* anchors  = (const float*)d_in[2];
  float* out = (float*)d_out;

  // folded keys: key(42) = (0,42); fold_in(k, d) = threefry block on (0, d)
  uint32_t kp0, kp1, kn0, kn1;
  tf2x32(0u, 42u, 0u, 0u, kp0, kp1);   // pri_pos key
  tf2x32(0u, 42u, 0u, 1u, kn0, kn1);   // pri_neg key

  // ws layout: [256B counters][pos_key B*cap_pos*8][neg_key B*cap_neg*8]
  long cap_pos = 32768, cap_neg = 8192;
  while (cap_pos > 2048 &&
         256 + (size_t)BB * 8 * (size_t)(cap_pos + cap_neg) > ws_size) {
    cap_pos >>= 1; cap_neg >>= 1;
  }
  char* base = (char*)d_ws;
  int* counters = (int*)base;
  unsigned long long* pos_key = (unsigned long long*)(base + 256);
  unsigned long long* neg_key = pos_key + (size_t)BB * cap_pos;

  hipMemsetAsync(d_ws, 0, 256, stream);
  k_scan<<<BB * (AA / BLK_ANCH), SCAN_NT, 0, stream>>>(
      gt_boxes, gt_cls, anchors, counters, pos_key, neg_key,
      (int)cap_pos, (int)cap_neg, kp0, kp1, kn0, kn1);
  k_sel<<<BB * 2, NT_SEL, 0, stream>>>(
      gt_boxes, gt_cls, anchors, counters, pos_key, neg_key,
      (int)cap_pos, (int)cap_neg, out);
}

// Round 13
// 85.623 us; speedup vs baseline: 1.0612x; 1.0241x over previous
//
#include <hip/hip_runtime.h>
#include <stdint.h>

// Keep float math un-fused so IoU bits match the numpy/JAX reference near the
// 0.6 / 0.3 mask thresholds.
#pragma clang fp contract(off)

#define BB 4
#define GG 64
#define AA 262144
#define TT 256
#define PP 128
#define APT 4                 // anchors per thread (r10-verified best point)
#define NEG_THRESH 0.99f      // stored negs ~2600/batch; top-256 boundary ~0.9988
#define NBINS 2048
#define CANDCAP 1024
#define NT_SEL 512
#define CB (NBINS / NT_SEL)   // bins per chunk = 4
#define SCAN_NT 256
#define BLK_ANCH (SCAN_NT * APT)   // 1024 anchors per block
#define GUNROLL 8             // gt count padded to a multiple of 8
#define NG_FAST 40            // dataset invariant: arange(64)<40 -> 40 valid gts

// ---------------- Threefry-2x32 (matches jax._src.prng) ----------------
__host__ __device__ inline void tf2x32(uint32_t k0, uint32_t k1,
                                       uint32_t x0, uint32_t x1,
                                       uint32_t& o0, uint32_t& o1) {
  const uint32_t ks2 = k0 ^ k1 ^ 0x1BD11BDAu;
  x0 += k0; x1 += k1;
#define TF_R(r) { x0 += x1; x1 = (x1 << (r)) | (x1 >> (32 - (r))); x1 ^= x0; }
  TF_R(13) TF_R(15) TF_R(26) TF_R(6)
  x0 += k1;  x1 += ks2 + 1u;
  TF_R(17) TF_R(29) TF_R(16) TF_R(24)
  x0 += ks2; x1 += k0 + 2u;
  TF_R(13) TF_R(15) TF_R(26) TF_R(6)
  x0 += k0;  x1 += k1 + 3u;
  TF_R(17) TF_R(29) TF_R(16) TF_R(24)
  x0 += k1;  x1 += ks2 + 4u;
  TF_R(13) TF_R(15) TF_R(26) TF_R(6)
  x0 += ks2; x1 += k0 + 5u;
#undef TF_R
  o0 = x0; o1 = x1;
}

// jax.random.uniform, threefry_partitionable path: bits[i] = o0^o1 of
// block(key, (0, i)); value = bitcast((bits>>9)|0x3f800000) - 1.0
__device__ inline float tf_uniform(uint32_t k0, uint32_t k1, uint32_t idx) {
  uint32_t o0, o1;
  tf2x32(k0, k1, 0u, idx, o0, o1);
  uint32_t bits = o0 ^ o1;
  return __uint_as_float((bits >> 9) | 0x3f800000u) - 1.0f;
}

// key layout: [63:32] priority float bits, [23:6] ~a (18 bits), [5:0] gt idx.
// Desc sort == JAX top_k order (value desc, index asc); a unique -> g bits
// never decide order.
__device__ inline unsigned long long make_key(float pri, int a, int g) {
  const uint32_t inv = (uint32_t)a ^ 0x3FFFFu;
  return ((unsigned long long)__float_as_uint(pri) << 32) |
         ((unsigned long long)inv << 6) | (unsigned)g;
}

// Compile-time-trip scan body (r7's proven codegen shape: full flatten,
// cross-iteration ds_read pipelining, VGPR ~32). Instantiated ONCE (NG=40)
// to avoid r11's multi-instantiation regalloc bloat.
template <int NG>
__device__ inline void scan_gts_ct(const float4* __restrict__ s_gt,
                                   const float* __restrict__ s_area,
                                   const float4* an, const float* area_an,
                                   float* best, int* bestg) {
#pragma unroll
  for (int g = 0; g < NG; ++g) {
    const float4 gb = s_gt[g];
    const float area_gt = s_area[g];
#pragma unroll
    for (int k = 0; k < APT; ++k) {
      float iw = fmaxf(0.f, fminf(gb.w, an[k].w) - fmaxf(gb.y, an[k].y));
      float ih = fmaxf(0.f, fminf(gb.z, an[k].z) - fmaxf(gb.x, an[k].x));
      float inter = iw * ih;
      float iou = inter / (area_gt + area_an[k] - inter);
      if (iou > best[k]) { best[k] = iou; bestg[k] = g; }
    }
  }
}

// ---------------- Kernel 1: IoU scan + block-aggregated candidate store ----
__global__ __launch_bounds__(SCAN_NT) void k_scan(
    const float* __restrict__ gt_boxes,   // (B, G, 5)
    const float* __restrict__ gt_cls,     // (B, G, 3)
    const float* __restrict__ anchors,    // (B, A, 4)
    int* __restrict__ counters,           // per batch: npos, nneg, spos, sneg
    unsigned long long* __restrict__ pos_key,
    unsigned long long* __restrict__ neg_key,
    int cap_pos, int cap_neg,
    uint32_t kp0, uint32_t kp1, uint32_t kn0, uint32_t kn1) {
  __shared__ float4 s_gt[GG + GUNROLL];   // COMPACTED valid gts + zero pads
  __shared__ float s_area[GG + GUNROLL];
  __shared__ int s_gidx[GG];        // compacted slot -> original g
  __shared__ int s_ng;              // number of valid gts
  __shared__ unsigned long long l_buf[BLK_ANCH];  // pos from 0^, neg from top v
  __shared__ int l_cnt[4];     // pos stored, neg stored, npos, nneg
  __shared__ int l_base[2];

  const int BPB = AA / BLK_ANCH;                     // blocks per batch = 256
  const int b = blockIdx.x / BPB;
  const int base = (blockIdx.x % BPB) * BLK_ANCH;
  const int tid = threadIdx.x;
  const int lane = tid & 63;
  const unsigned long long below = (lane == 0) ? 0ull : (~0ull >> (64 - lane));

  // Valid-GT compaction (wave 0 only; GG == 64 == one wave).
  // Invalid gts give IoU == +0.0 (zero box) in the reference path -> can't
  // flip pos/neg or win argmax (strict >, iou >= 0) -> skipping is exact.
  // Pads (zero boxes after the compacted list) are inert the same way.
  if (tid < GG) {
    bool v = gt_cls[(size_t)(b * GG + tid) * 3 + 2] != -1.0f;
    unsigned long long mv = __ballot(v);
    int cnt = __popcll(mv);
    if (v) {
      const float* gb = gt_boxes + (size_t)(b * GG + tid) * 5;
      int pos = __popcll(mv & below);
      s_gt[pos] = make_float4(gb[0], gb[1], gb[2], gb[3]);
      s_area[pos] = (gb[3] - gb[1]) * (gb[2] - gb[0]);
      s_gidx[pos] = tid;
    }
    if (tid < GUNROLL) {
      s_gt[cnt + tid] = make_float4(0.f, 0.f, 0.f, 0.f);
      s_area[cnt + tid] = 0.f;
    }
    if (tid == 0) s_ng = cnt;
  }
  if (tid < 4) l_cnt[tid] = 0;
  __syncthreads();
  const int ng = s_ng;
  const int ng8 = (ng + GUNROLL - 1) & ~(GUNROLL - 1);

  float4 an[APT];
  float area_an[APT], best[APT];
  int bestg[APT];
  const float4* ap = (const float4*)anchors + (size_t)b * AA + base + tid;
#pragma unroll
  for (int k = 0; k < APT; ++k) {
    an[k] = ap[k * SCAN_NT];
    area_an[k] = (an[k].w - an[k].y) * (an[k].z - an[k].x);
    best[k] = -1.0f;
    bestg[k] = 0;
  }

  // Fast path: this dataset always has exactly 40 valid gts (tag =
  // arange(64) < 40), batch-uniform -> no divergence. Single compile-time
  // instantiation reproduces r7's 71%-busy pipelined codegen at 5/8 work.
  // Generic fallback (r10-verified runtime loop) keeps correctness for any ng.
  if (ng == NG_FAST) {
    scan_gts_ct<NG_FAST>(s_gt, s_area, an, area_an, best, bestg);
  } else {
    for (int gi = 0; gi < ng8; gi += GUNROLL) {
#pragma unroll
      for (int u = 0; u < GUNROLL; ++u) {
        const float4 gb = s_gt[gi + u];
        const float area_gt = s_area[gi + u];
#pragma unroll
        for (int k = 0; k < APT; ++k) {
          float iw = fmaxf(0.f, fminf(gb.w, an[k].w) - fmaxf(gb.y, an[k].y));
          float ih = fmaxf(0.f, fminf(gb.z, an[k].z) - fmaxf(gb.x, an[k].x));
          float inter = iw * ih;
          float iou = inter / (area_gt + area_an[k] - inter);
          if (iou > best[k]) { best[k] = iou; bestg[k] = gi + u; }
        }
      }
    }
  }

  // classify + stage candidates in LDS.
  // ALL ballots/shfls/leader-atomics execute at full-wave convergence;
  // only the LDS store itself is predicated.
#pragma unroll
  for (int k = 0; k < APT; ++k) {
    const int a = base + k * SCAN_NT + tid;
    const uint32_t flat = (uint32_t)(b * AA + a);
    const bool isp = best[k] > 0.6f;
    const bool isn = best[k] < 0.3f;

    float prin = 0.f;
    bool store_n = false;
    if (isn) {
      prin = tf_uniform(kn0, kn1, flat);
      store_n = prin > NEG_THRESH;
    }

    const unsigned long long mp = __ballot(isp);
    const unsigned long long mnAll = __ballot(isn);
    const unsigned long long mn = __ballot(store_n);

    int wbase_p = 0, wbase_n = 0;
    if (lane == 0) {
      const int cp = __popcll(mp);
      const int cs = __popcll(mn);
      const int cnAll = __popcll(mnAll);
      if (cp) { wbase_p = atomicAdd(&l_cnt[0], cp); atomicAdd(&l_cnt[2], cp); }
      if (cs) wbase_n = atomicAdd(&l_cnt[1], cs);
      if (cnAll) atomicAdd(&l_cnt[3], cnAll);
    }
    wbase_p = __shfl(wbase_p, 0);
    wbase_n = __shfl(wbase_n, 0);

    // pos + stored-neg are mutually exclusive per anchor, so the two ends
    // of l_buf can never collide (total <= BLK_ANCH by construction).
    if (isp) {
      float pri = tf_uniform(kp0, kp1, flat);
      l_buf[wbase_p + __popcll(mp & below)] =
          make_key(pri, a, s_gidx[bestg[k]]);
    }
    if (store_n) {
      l_buf[BLK_ANCH - 1 - (wbase_n + __popcll(mn & below))] =
          make_key(prin, a, 0);
    }
  }
  __syncthreads();

  // one returning device atomic per non-empty list per block
  if (tid == 0) {
    l_base[0] = l_cnt[0] ? atomicAdd(&counters[b * 4 + 2], l_cnt[0]) : 0;
    if (l_cnt[2]) atomicAdd(&counters[b * 4 + 0], l_cnt[2]);
  } else if (tid == 64) {
    l_base[1] = l_cnt[1] ? atomicAdd(&counters[b * 4 + 3], l_cnt[1]) : 0;
    if (l_cnt[3]) atomicAdd(&counters[b * 4 + 1], l_cnt[3]);
  }
  __syncthreads();

  // coalesced copy-out (prefix [0,cap) stays fully populated: a straddling
  // block writes only its in-range part; selection is order-independent)
  for (int i = tid; i < l_cnt[0]; i += SCAN_NT) {
    int dst = l_base[0] + i;
    if (dst < cap_pos) pos_key[(size_t)b * cap_pos + dst] = l_buf[i];
  }
  for (int i = tid; i < l_cnt[1]; i += SCAN_NT) {
    int dst = l_base[1] + i;
    if (dst < cap_neg)
      neg_key[(size_t)b * cap_neg + dst] = l_buf[BLK_ANCH - 1 - i];
  }
}

// ---------------- Kernel 2: exact histogram top-k + fused outputs ----------
// One block per (batch, phase). Phase 0 (pos) writes slots [0,pos_count) and
// the tail [pos_count+neg_count, 256) plus scalars/hits; phase 1 (neg)
// writes slots [pos_count, pos_count+neg_count). Disjoint, complete cover.
// out layout (flat float32):
//   class_ids [0, 2048), deltas [2048, 6144), indices [6144, 8192),
//   gt_num [8192, 8196), pos_count [8196, 8200), miss [8200, 8204)
__global__ __launch_bounds__(NT_SEL) void k_sel(
    const float* __restrict__ gt_boxes,
    const float* __restrict__ gt_cls,
    const float* __restrict__ anchors,
    const int* __restrict__ counters,
    const unsigned long long* __restrict__ pos_key,
    const unsigned long long* __restrict__ neg_key,
    int cap_pos, int cap_neg,
    float* __restrict__ out) {
  const int b = blockIdx.x >> 1;
  const int phase = blockIdx.x & 1;
  const int tid = threadIdx.x;

  __shared__ int hist[NBINS];
  __shared__ int chunk[NT_SEL];
  __shared__ unsigned long long cand[CANDCAP];
  __shared__ float4 s_gt[GG];
  __shared__ float s_cls0[GG], s_cls1[GG];
  __shared__ int s_valid[GG];
  __shared__ unsigned int hit_lo, hit_hi;
  __shared__ int s_t, s_cnt;

  if (tid < GG) {
    const float* gb = gt_boxes + (size_t)(b * GG + tid) * 5;
    s_gt[tid] = make_float4(gb[0], gb[1], gb[2], gb[3]);
    s_cls0[tid] = gt_cls[(size_t)(b * GG + tid) * 3 + 0];
    s_cls1[tid] = gt_cls[(size_t)(b * GG + tid) * 3 + 1];
    s_valid[tid] = (gt_cls[(size_t)(b * GG + tid) * 3 + 2] != -1.0f) ? 1 : 0;
  }
  if (tid == 0) { hit_lo = 0u; hit_hi = 0u; }

  const int npos = counters[b * 4 + 0];
  const int nneg = counters[b * 4 + 1];
  const int sp = min(counters[b * 4 + 2], cap_pos);
  const int sn = min(counters[b * 4 + 3], cap_neg);
  const int pos_count = min(min(PP, npos), sp);
  const int neg_count = min(min(TT - pos_count, nneg), sn);

  const unsigned long long* keys =
      phase ? neg_key + (size_t)b * cap_neg : pos_key + (size_t)b * cap_pos;
  const int n = phase ? sn : sp;
  const int kk = phase ? neg_count : pos_count;

  for (int i = tid; i < NBINS; i += NT_SEL) hist[i] = 0;
  if (tid == 0) { s_cnt = 0; s_t = (kk == 0) ? NBINS : 0; }
  __syncthreads();

  for (int i = tid; i < n; i += NT_SEL) {
    float pri = __uint_as_float((uint32_t)(keys[i] >> 32));
    int bin = min(NBINS - 1, (int)(pri * (float)NBINS));
    atomicAdd(&hist[bin], 1);
  }
  __syncthreads();

  // parallel suffix scan over 512 chunk sums (4 bins/chunk)
  {
    int c = 0;
#pragma unroll
    for (int u = 0; u < CB; ++u) c += hist[tid * CB + u];
    chunk[tid] = c;
    __syncthreads();
    for (int s = 1; s < NT_SEL; s <<= 1) {
      int v = chunk[tid];
      int add = (tid + s < NT_SEL) ? chunk[tid + s] : 0;
      __syncthreads();
      chunk[tid] = v + add;
      __syncthreads();
    }
    // t = max{bin : suffix(bin) >= kk}; crossing chunk unique (monotone).
    if (kk > 0) {
      int Scur = chunk[tid];
      int Snext = (tid + 1 < NT_SEL) ? chunk[tid + 1] : 0;
      if (Scur >= kk && Snext < kk) {
        int acc = Snext;
        for (int u = CB - 1; u >= 0; --u) {
          acc += hist[tid * CB + u];
          if (acc >= kk) { s_t = tid * CB + u; break; }
        }
      }
      // if chunk[0] < kk (n < kk): no chunk qualifies, s_t stays 0 -> all n
    }
  }
  __syncthreads();
  const int t = s_t;

  for (int i = tid; i < n; i += NT_SEL) {
    unsigned long long key = keys[i];
    float pri = __uint_as_float((uint32_t)(key >> 32));
    int bin = min(NBINS - 1, (int)(pri * (float)NBINS));
    if (bin >= t) {
      int slot = atomicAdd(&s_cnt, 1);
      if (slot < CANDCAP) cand[slot] = key;
    }
  }
  __syncthreads();
  const int cnt = min(s_cnt, CANDCAP);  // cnt >= kk by suffix construction

  unsigned m = 1;
  while (m < (unsigned)cnt) m <<= 1;   // sort size: next pow2 of cnt
  for (int i = tid; i < (int)m; i += NT_SEL)
    if (i >= cnt) cand[i] = 0ull;
  __syncthreads();

  for (unsigned kq = 2; kq <= m; kq <<= 1) {
    for (unsigned s = kq >> 1; s > 0; s >>= 1) {
      for (unsigned i = tid; i < m; i += NT_SEL) {
        unsigned p = i ^ s;
        if (p > i) {
          unsigned long long x = cand[i], y = cand[p];
          if (((i & kq) == 0) ? (x < y) : (x > y)) { cand[i] = y; cand[p] = x; }
        }
      }
      __syncthreads();
    }
  }
  // cand[0..kk) now holds this phase's selected keys in JAX top_k order.

  // ---- fused output writing ----
  if (tid < TT) {
    const int j = tid;
    if (phase == 0) {
      const bool isp = j < pos_count;
      const bool tail = j >= pos_count + neg_count;   // tag -1 region
      if (isp || tail) {
        float c0 = 0.f, c1 = 0.f, d0 = 0.f, d1 = 0.f, d2 = 0.f, d3 = 0.f;
        int out_idx = -1, tag = -1;
        if (isp) {
          const unsigned long long key = cand[j];
          const int a = (int)((((unsigned)(key >> 6)) & 0x3FFFFu) ^ 0x3FFFFu);
          const int g = (int)(key & 63ull);
          out_idx = a; tag = 1;
          c0 = s_cls0[g]; c1 = s_cls1[g];
          float4 an = ((const float4*)anchors)[(size_t)b * AA + a];
          float4 gb = s_gt[g];
          float h = an.z - an.x, w = an.w - an.y;
          float gh = gb.z - gb.x, gw = gb.w - gb.y;
          float cy = (an.z + an.x) * 0.5f, cx = (an.w + an.y) * 0.5f;
          float gcy = (gb.z + gb.x) * 0.5f, gcx = (gb.w + gb.y) * 0.5f;
          d0 = ((gcy - cy) / h) / 0.1f;
          d1 = ((gcx - cx) / w) / 0.1f;
          d2 = logf(gh / h) / 0.2f;
          d3 = logf(gw / w) / 0.2f;
          if (g < 32) atomicOr(&hit_lo, 1u << g);
          else        atomicOr(&hit_hi, 1u << (g - 32));
        }
        float* cls_out = out + ((size_t)b * TT + j) * 2;
        cls_out[0] = c0; cls_out[1] = c1;
        float* del_out = out + 2048 + ((size_t)b * TT + j) * 4;
        del_out[0] = d0; del_out[1] = d1; del_out[2] = d2; del_out[3] = d3;
        float* idx_out = out + 6144 + ((size_t)b * TT + j) * 2;
        idx_out[0] = (float)out_idx; idx_out[1] = (float)tag;
      }
    } else {
      const bool isn = (j >= pos_count) && (j < pos_count + neg_count);
      if (isn) {
        const unsigned long long key = cand[j - pos_count];
        const int a = (int)((((unsigned)(key >> 6)) & 0x3FFFFu) ^ 0x3FFFFu);
        float* cls_out = out + ((size_t)b * TT + j) * 2;
        cls_out[0] = 1.f; cls_out[1] = 0.f;
        float* del_out = out + 2048 + ((size_t)b * TT + j) * 4;
        del_out[0] = 0.f; del_out[1] = 0.f; del_out[2] = 0.f; del_out[3] = 0.f;
        float* idx_out = out + 6144 + ((size_t)b * TT + j) * 2;
        idx_out[0] = (float)a; idx_out[1] = 0.f;
      }
    }
  }

  __syncthreads();
  if (phase == 0 && tid == 0) {
    int gn = 0;
    for (int g = 0; g < GG; ++g) gn += s_valid[g];
    float hits = (float)(__popc(hit_lo) + __popc(hit_hi));
    out[8192 + b] = (float)gn;
    out[8196 + b] = (float)pos_count;
    out[8200 + b] = (float)gn - hits;
  }
}

// ---------------- host ----------------
extern "C" void kernel_launch(void* const* d_in, const int* in_sizes, int n_in,
                              void* d_out, int out_size, void* d_ws, size_t ws_size,
                              hipStream_t stream) {
  const float* gt_boxes = (const float*)d_in[0];
  const float* gt_cls   = (const float*)d_in[1];
  const float* anchors  = (const float*)d_in[2];
  float* out = (float*)d_out;

  // folded keys: key(42) = (0,42); fold_in(k, d) = threefry block on (0, d)
  uint32_t kp0, kp1, kn0, kn1;
  tf2x32(0u, 42u, 0u, 0u, kp0, kp1);   // pri_pos key
  tf2x32(0u, 42u, 0u, 1u, kn0, kn1);   // pri_neg key

  // ws layout: [256B counters][pos_key B*cap_pos*8][neg_key B*cap_neg*8]
  long cap_pos = 32768, cap_neg = 8192;
  while (cap_pos > 2048 &&
         256 + (size_t)BB * 8 * (size_t)(cap_pos + cap_neg) > ws_size) {
    cap_pos >>= 1; cap_neg >>= 1;
  }
  char* base = (char*)d_ws;
  int* counters = (int*)base;
  unsigned long long* pos_key = (unsigned long long*)(base + 256);
  unsigned long long* neg_key = pos_key + (size_t)BB * cap_pos;

  hipMemsetAsync(d_ws, 0, 256, stream);
  k_scan<<<BB * (AA / BLK_ANCH), SCAN_NT, 0, stream>>>(
      gt_boxes, gt_cls, anchors, counters, pos_key, neg_key,
      (int)cap_pos, (int)cap_neg, kp0, kp1, kn0, kn1);
  k_sel<<<BB * 2, NT_SEL, 0, stream>>>(
      gt_boxes, gt_cls, anchors, counters, pos_key, neg_key,
      (int)cap_pos, (int)cap_neg, out);
}